// Round 5
// baseline (271.096 us; speedup 1.0000x reference)
//
#include <hip/hip_runtime.h>

// Problem constants
#define BN 32768
#define KN 5
#define LN 128
#define HN 3
#define ROWS (BN*KN)        // 163840
#define BK ROWS
#define MT 32               // rows per tile
#define TILES (ROWS/MT)     // 5120
#define WGS 512
#define TPW (TILES/WGS)     // 10 tiles per workgroup
#define THREADS 512         // 8 waves
#define HSTR 136            // h row stride (bf16): 128 + 8 pad
#define ESTR 40             // emb row stride (bf16): 16 emb + 16 zero + 8 pad
#define XSTR 34             // x_proj row stride (bf16): 32 m + 2 pad (68B: bank-free)

using bf16x8 = __attribute__((ext_vector_type(8))) __bf16;
using f32x4  = __attribute__((ext_vector_type(4))) float;
using u16x8  = __attribute__((ext_vector_type(8))) unsigned short;
using u16x4  = __attribute__((ext_vector_type(4))) unsigned short;

__device__ inline unsigned short f2bf(float x) {
    union { float f; unsigned u; } v; v.f = x;
    unsigned r = v.u + 0x7FFFu + ((v.u >> 16) & 1u);   // RNE
    return (unsigned short)(r >> 16);
}
__device__ inline float bf2f(unsigned short b) {
    union { unsigned u; float f; } v; v.u = ((unsigned)b) << 16; return v.f;
}
__device__ inline float sigm(float x) {
    return __builtin_amdgcn_rcpf(1.0f + __builtin_amdgcn_exp2f(-1.44269504089f * x));
}
__device__ inline float tanh_(float x) {
    return 1.0f - 2.0f * __builtin_amdgcn_rcpf(1.0f + __builtin_amdgcn_exp2f(2.88539008178f * x));
}
__device__ inline f32x4 splat4(float x) { f32x4 r; r[0]=x; r[1]=x; r[2]=x; r[3]=x; return r; }

__global__ __launch_bounds__(THREADS, 4)   // total regs <= 128 -> 2 wg/CU
void wahead_kernel(const float* __restrict__ z,   const float* __restrict__ anchors,
                   const float* __restrict__ W1,  const float* __restrict__ b1,
                   const float* __restrict__ W2,  const float* __restrict__ b2,
                   const float* __restrict__ Wih, const float* __restrict__ Whh,
                   const float* __restrict__ bih, const float* __restrict__ bhh,
                   const float* __restrict__ Wp,  const float* __restrict__ bp,
                   const float* __restrict__ Wr,  const float* __restrict__ br,
                   float* __restrict__ out)
{
    __shared__ unsigned short sH[2 * MT * HSTR];   // ping-pong h (bf16), 17.4 KB
    __shared__ unsigned short sE[MT * ESTR];       // emb tile, zero-padded to k=32
    __shared__ unsigned short sXP[512 * XSTR];     // x_proj + biases, bf16, [n][m], 34.8 KB
    __shared__ float sW1[32], sb1[16], sW2[16 * 17], sb2[16], sWp[128], sWr[384];

    const int tid  = threadIdx.x;
    const int wv   = tid >> 6;       // wave 0..7: owns 16 l-cols of each gate
    const int lane = tid & 63;
    const int quad = lane >> 4;
    const int cc   = lane & 15;

    // ---- stage small constant weights into LDS ----
    if (tid < 32)  sW1[tid] = W1[tid];
    if (tid < 16)  { sb1[tid] = b1[tid]; sb2[tid] = b2[tid]; }
    if (tid < 256) sW2[(tid >> 4) * 17 + (tid & 15)] = W2[tid];
    if (tid < 128) sWp[tid] = Wp[tid];
    if (tid < 384) sWr[tid] = Wr[tid];

    // ---- W_hh B-fragments (K=128, 4 k-tiles of 32), bf16, pinned in AGPRs ----
    // B layout (16x16x32): n = lane&15, k = quad*8 + j
    bf16x8 Bh[4][4];
    float  biasv[4];
    #pragma unroll
    for (int t = 0; t < 4; ++t) {
        const int n = t * 128 + wv * 16 + cc;
        biasv[t] = bih[n] + bhh[n];
        #pragma unroll
        for (int kt = 0; kt < 4; ++kt) {
            const int k0 = kt * 32 + quad * 8;
            const float4 p0 = *reinterpret_cast<const float4*>(Whh + n * 128 + k0);
            const float4 p1 = *reinterpret_cast<const float4*>(Whh + n * 128 + k0 + 4);
            union { bf16x8 bv; unsigned short us[8]; } pk;
            pk.us[0]=f2bf(p0.x); pk.us[1]=f2bf(p0.y); pk.us[2]=f2bf(p0.z); pk.us[3]=f2bf(p0.w);
            pk.us[4]=f2bf(p1.x); pk.us[5]=f2bf(p1.y); pk.us[6]=f2bf(p1.z); pk.us[7]=f2bf(p1.w);
            Bh[t][kt] = pk.bv;
        }
    }
    // Pin the 64 B-regs into the accumulator half of the register file so the
    // arch half stays under 64 -> 4 waves/SIMD at launch_bounds(512,4).
    #pragma unroll
    for (int t = 0; t < 4; ++t)
        #pragma unroll
        for (int kt = 0; kt < 4; ++kt)
            asm volatile("" : "+a"(Bh[t][kt]));

    const float bpv = bp[0];
    const float br0 = br[0], br1 = br[1], br2 = br[2];

    __syncthreads();   // consts staged

    const int erow = tid >> 4;   // 0..31
    const int esub = tid & 15;   // 0..15

    #pragma unroll 1
    for (int ti = 0; ti < TPW; ++ti) {
        const int tile = blockIdx.x * TPW + ti;
        const int r0g  = tile * MT;

        // -------- staging: emb MLP -> sE (zero-padded), z -> sH[0] --------
        {
            const int gr = r0g + erow;
            const float ax = anchors[gr * 2], ay = anchors[gr * 2 + 1];
            float acc_e = sb2[esub];
            #pragma unroll
            for (int hh = 0; hh < 16; ++hh) {
                float pre = fmaf(sW1[hh * 2], ax, fmaf(sW1[hh * 2 + 1], ay, sb1[hh]));
                pre = fmaxf(pre, 0.0f);
                acc_e = fmaf(pre, sW2[esub * 17 + hh], acc_e);
            }
            sE[erow * ESTR + esub]      = f2bf(acc_e);
            sE[erow * ESTR + 16 + esub] = 0;           // zero pad k=16..31
            const unsigned b_idx = (unsigned)gr / 5u;
            const float4* zp = reinterpret_cast<const float4*>(z + (size_t)b_idx * 128 + esub * 8);
            const float4 z0 = zp[0], z1 = zp[1];
            union { u16x8 v; unsigned short us[8]; } zz;
            zz.us[0]=f2bf(z0.x); zz.us[1]=f2bf(z0.y); zz.us[2]=f2bf(z0.z); zz.us[3]=f2bf(z0.w);
            zz.us[4]=f2bf(z1.x); zz.us[5]=f2bf(z1.y); zz.us[6]=f2bf(z1.z); zz.us[7]=f2bf(z1.w);
            *reinterpret_cast<u16x8*>(&sH[erow * HSTR + esub * 8]) = zz.v;
        }

        __syncthreads();   // sE / sH[0] ready; also: all sXP reads of prev tile done

        // -------- x_proj = emb @ Wih^T + (bih+bhh) -> sXP (bf16) --------
        {
            const float* wp = Wih;
            asm volatile("" : "+s"(wp));   // defeat LICM: Wih frags not kept live
            #pragma unroll
            for (int t = 0; t < 4; ++t) {
                const int n = t * 128 + wv * 16 + cc;
                // quads 2,3 multiply against zero A-cols; (quad&1) keeps addr valid
                const float4 p0 = *reinterpret_cast<const float4*>(wp + n * 16 + (quad & 1) * 8);
                const float4 p1 = *reinterpret_cast<const float4*>(wp + n * 16 + (quad & 1) * 8 + 4);
                union { bf16x8 bv; unsigned short us[8]; } pk;
                pk.us[0]=f2bf(p0.x); pk.us[1]=f2bf(p0.y); pk.us[2]=f2bf(p0.z); pk.us[3]=f2bf(p0.w);
                pk.us[4]=f2bf(p1.x); pk.us[5]=f2bf(p1.y); pk.us[6]=f2bf(p1.z); pk.us[7]=f2bf(p1.w);
                #pragma unroll
                for (int mt = 0; mt < 2; ++mt) {
                    const bf16x8 ae = *reinterpret_cast<const bf16x8*>(
                        &sE[(mt * 16 + cc) * ESTR + quad * 8]);
                    f32x4 xa = splat4(biasv[t]);
                    xa = __builtin_amdgcn_mfma_f32_16x16x32_bf16(ae, pk.bv, xa, 0, 0, 0);
                    union { u16x4 v; unsigned short us[4]; } ov;
                    #pragma unroll
                    for (int r = 0; r < 4; ++r) ov.us[r] = f2bf(xa[r]);
                    *reinterpret_cast<u16x4*>(&sXP[n * XSTR + mt * 16 + quad * 4]) = ov.v;
                }
            }
        }

        float cst[2][4] = {{0,0,0,0},{0,0,0,0}};

        #pragma unroll
        for (int s = 0; s < HN; ++s) {
            const int cur = s & 1;
            const int nxt = cur ^ 1;
            __syncthreads();   // sXP (s==0) / previous-step h writes visible

            #pragma unroll
            for (int mt = 0; mt < 2; ++mt) {
                // acc init from sXP (x_proj + biases)
                f32x4 acc[4];
                #pragma unroll
                for (int t = 0; t < 4; ++t) {
                    const int n = t * 128 + wv * 16 + cc;
                    const u16x4 xv = *reinterpret_cast<const u16x4*>(
                        &sXP[n * XSTR + mt * 16 + quad * 4]);
                    #pragma unroll
                    for (int r = 0; r < 4; ++r) acc[t][r] = bf2f(xv[r]);
                }
                // h @ Whh^T : 4 k-tiles, B from AGPR
                #pragma unroll
                for (int kt = 0; kt < 4; ++kt) {
                    const bf16x8 a = *reinterpret_cast<const bf16x8*>(
                        &sH[cur * MT * HSTR + (mt * 16 + cc) * HSTR + kt * 32 + quad * 8]);
                    #pragma unroll
                    for (int t = 0; t < 4; ++t)
                        acc[t] = __builtin_amdgcn_mfma_f32_16x16x32_bf16(a, Bh[t][kt], acc[t], 0, 0, 0);
                }
                // pointwise; C layout: col = lane&15 (-> l), row = quad*4 + r
                const int lcol = wv * 16 + cc;
                #pragma unroll
                for (int r = 0; r < 4; ++r) {
                    const float ig = sigm(acc[0][r]);
                    const float fg = sigm(acc[1][r]);
                    const float gg = tanh_(acc[2][r]);
                    const float og = sigm(acc[3][r]);
                    const float cn = fmaf(fg, cst[mt][r], ig * gg);
                    cst[mt][r] = cn;
                    const float hn = og * tanh_(cn);
                    const int m = mt * 16 + quad * 4 + r;
                    sH[nxt * MT * HSTR + m * HSTR + lcol] = f2bf(hn);
                }
            }
        }

        __syncthreads();   // final h (buffer 1) complete

        // -------- epilogue: heads (read bf16 h) --------
        {
            const int row = tid >> 4;    // 0..31
            const int j   = tid & 15;    // 16 threads per row, 8 l each
            const u16x8 hv8 = *reinterpret_cast<const u16x8*>(
                &sH[1 * MT * HSTR + row * HSTR + j * 8]);
            float p = 0.f, q0 = 0.f, q1 = 0.f, q2 = 0.f;
            #pragma unroll
            for (int u = 0; u < 8; ++u) {
                const int l = j * 8 + u;
                const float hv = bf2f(hv8[u]);
                p  = fmaf(hv, sWp[l], p);
                q0 = fmaf(hv, sWr[l], q0);
                q1 = fmaf(hv, sWr[128 + l], q1);
                q2 = fmaf(hv, sWr[256 + l], q2);
            }
            #pragma unroll
            for (int m = 1; m < 16; m <<= 1) {
                p  += __shfl_xor(p,  m, 64);
                q0 += __shfl_xor(q0, m, 64);
                q1 += __shfl_xor(q1, m, 64);
                q2 += __shfl_xor(q2, m, 64);
            }
            if (j == 0) {
                const int gr = r0g + row;
                const float prog  = p + bpv;
                const float rr0 = q0 + br0, rr1 = q1 + br1, rr2 = q2 + br2;
                const float rmean = (rr0 + rr1 + rr2) * (1.0f / 3.0f);
                const float s0 = sigm(rr0), s1 = sigm(rr1), s2 = sigm(rr2);
                const float sm = (s0 + s1 + s2) * (1.0f / 3.0f);
                const float d0 = s0 - sm, d1 = s1 - sm, d2 = s2 - sm;
                const float unc = (d0 * d0 + d1 * d1 + d2 * d2) * 0.5f;   // ddof=1
                out[gr]          = rmean;
                out[BK + gr]     = prog;
                out[2 * BK + gr] = unc;
                out[3 * BK + gr] = rr0;
                out[4 * BK + gr] = rr1;
                out[5 * BK + gr] = rr2;
            }
        }
        // next-tile staging writes sE + sH[0]; epilogue reads sH[1] (disjoint).
        // All sXP/sE reads of this tile complete before the next stage-sync.
    }
}

extern "C" void kernel_launch(void* const* d_in, const int* in_sizes, int n_in,
                              void* d_out, int out_size, void* d_ws, size_t ws_size,
                              hipStream_t stream) {
    const float* z       = (const float*)d_in[0];
    const float* anchors = (const float*)d_in[1];
    const float* W1      = (const float*)d_in[2];
    const float* b1      = (const float*)d_in[3];
    const float* W2      = (const float*)d_in[4];
    const float* b2      = (const float*)d_in[5];
    const float* Wih     = (const float*)d_in[6];
    const float* Whh     = (const float*)d_in[7];
    const float* bih     = (const float*)d_in[8];
    const float* bhh     = (const float*)d_in[9];
    const float* Wp      = (const float*)d_in[10];
    const float* bp      = (const float*)d_in[11];
    const float* Wr      = (const float*)d_in[12];
    const float* br      = (const float*)d_in[13];

    hipLaunchKernelGGL(wahead_kernel, dim3(WGS), dim3(THREADS), 0, stream,
                       z, anchors, W1, b1, W2, b2, Wih, Whh, bih, bhh,
                       Wp, bp, Wr, br, (float*)d_out);
}

// Round 6
// 213.038 us; speedup vs baseline: 1.2725x; 1.2725x over previous
//
#include <hip/hip_runtime.h>

// Problem constants
#define BN 32768
#define KN 5
#define LN 128
#define HN 3
#define ROWS (BN*KN)        // 163840
#define BK ROWS
#define MT 64               // rows per tile
#define TILES (ROWS/MT)     // 2560
#define WGS 512
#define TPW (TILES/WGS)     // 5 tiles per workgroup
#define THREADS 512         // 8 waves
#define ASTR 168            // A row stride bf16: [emb16|h128|zero16] + 8 pad
#define LOG2E 1.44269504089f

using bf16x8 = __attribute__((ext_vector_type(8))) __bf16;
using bf16x2 = __attribute__((ext_vector_type(2))) __bf16;
using f32x4  = __attribute__((ext_vector_type(4))) float;
using u16x8  = __attribute__((ext_vector_type(8))) unsigned short;

__device__ inline unsigned short f2bf(float x) {
    union { float f; unsigned u; } v; v.f = x;
    unsigned r = v.u + 0x7FFFu + ((v.u >> 16) & 1u);   // RNE
    return (unsigned short)(r >> 16);
}
#if __has_builtin(__builtin_amdgcn_cvt_pk_bf16_f32)
__device__ inline unsigned short f2bf_fast(float x) {
    union { bf16x2 v; unsigned short us[2]; } u;
    u.v = __builtin_amdgcn_cvt_pk_bf16_f32(x, x);
    return u.us[0];
}
#else
__device__ inline unsigned short f2bf_fast(float x) { return f2bf(x); }
#endif
__device__ inline float bf2f(unsigned short b) {
    union { unsigned u; float f; } v; v.u = ((unsigned)b) << 16; return v.f;
}
__device__ inline float sigm(float x) {
    return __builtin_amdgcn_rcpf(1.0f + __builtin_amdgcn_exp2f(-LOG2E * x));
}
__device__ inline f32x4 splat4(float x) { f32x4 r; r[0]=x; r[1]=x; r[2]=x; r[3]=x; return r; }

__global__ __launch_bounds__(THREADS, 2)   // 256-reg cap: no spills (R4-verified envelope)
void wahead_kernel(const float* __restrict__ z,   const float* __restrict__ anchors,
                   const float* __restrict__ W1,  const float* __restrict__ b1,
                   const float* __restrict__ W2,  const float* __restrict__ b2,
                   const float* __restrict__ Wih, const float* __restrict__ Whh,
                   const float* __restrict__ bih, const float* __restrict__ bhh,
                   const float* __restrict__ Wp,  const float* __restrict__ bp,
                   const float* __restrict__ Wr,  const float* __restrict__ br,
                   float* __restrict__ out)
{
    __shared__ unsigned short sA[2 * MT * ASTR];   // ping-pong [emb|h|0] bf16, 43 KB
    __shared__ float sW1[32], sb1[16], sW2[16 * 17], sb2[16], sWp[128], sWr[384];

    const int tid  = threadIdx.x;
    const int wv   = tid >> 6;       // wave 0..7: owns l-cols wv*16..wv*16+15 of each gate
    const int lane = tid & 63;
    const int quad = lane >> 4;
    const int cc   = lane & 15;

    // ---- stage small constant weights into LDS ----
    if (tid < 32)  sW1[tid] = W1[tid];
    if (tid < 16)  { sb1[tid] = b1[tid]; sb2[tid] = b2[tid]; }
    if (tid < 256) sW2[(tid >> 4) * 17 + (tid & 15)] = W2[tid];   // sW2[col*17+hh]
    if (tid < 128) sWp[tid] = Wp[tid];
    if (tid < 384) sWr[tid] = Wr[tid];

    // ---- stacked-B fragments [W_ih(16)|W_hh(128)|0(16)] with FOLDED gate scales ----
    // gates i,f,o scaled by -log2e; gate g scaled by +2*log2e, so exp2() applies
    // directly to the MFMA accumulators (no per-element pre-multiply).
    // B layout (16x16x32): n = lane&15, k = quad*8 + j
    bf16x8 Bf[4][5];
    float  biasv[4];
    #pragma unroll
    for (int t = 0; t < 4; ++t) {                      // gate i,f,g,o
        const float sc = (t == 2) ? (2.0f * LOG2E) : (-LOG2E);
        const int n = t * 128 + wv * 16 + cc;          // gate output col in [0,512)
        biasv[t] = sc * (bih[n] + bhh[n]);
        #pragma unroll
        for (int kt = 0; kt < 5; ++kt) {
            const int k0 = kt * 32 + quad * 8;
            float v[8];
            if (k0 < 16) {                             // W_ih region
                const float4 p0 = *reinterpret_cast<const float4*>(Wih + n * 16 + k0);
                const float4 p1 = *reinterpret_cast<const float4*>(Wih + n * 16 + k0 + 4);
                v[0]=p0.x; v[1]=p0.y; v[2]=p0.z; v[3]=p0.w;
                v[4]=p1.x; v[5]=p1.y; v[6]=p1.z; v[7]=p1.w;
            } else if (k0 < 144) {                     // W_hh region
                const float4 p0 = *reinterpret_cast<const float4*>(Whh + n * 128 + (k0 - 16));
                const float4 p1 = *reinterpret_cast<const float4*>(Whh + n * 128 + (k0 - 16) + 4);
                v[0]=p0.x; v[1]=p0.y; v[2]=p0.z; v[3]=p0.w;
                v[4]=p1.x; v[5]=p1.y; v[6]=p1.z; v[7]=p1.w;
            } else {                                   // zero pad k in [144,160)
                #pragma unroll
                for (int j = 0; j < 8; ++j) v[j] = 0.0f;
            }
            union { bf16x8 bv; unsigned short us[8]; } pk;
            #pragma unroll
            for (int j = 0; j < 8; ++j) pk.us[j] = f2bf(sc * v[j]);
            Bf[t][kt] = pk.bv;
        }
    }

    const float bpv = bp[0];
    const float br0 = br[0], br1 = br[1], br2 = br[2];

    __syncthreads();   // consts staged

    const int erow = tid >> 3;   // 0..63 (8 threads per row)
    const int esub = tid & 7;    // 0..7

    #pragma unroll 1
    for (int ti = 0; ti < TPW; ++ti) {
        const int tile = blockIdx.x * TPW + ti;
        const int r0g  = tile * MT;

        // -------- staging: emb MLP (2 cols/thread) + zero-pad + z --------
        {
            const int gr = r0g + erow;
            const float ax = anchors[gr * 2], ay = anchors[gr * 2 + 1];
            const int e0 = esub * 2;
            float a0 = sb2[e0], a1 = sb2[e0 + 1];
            #pragma unroll
            for (int hh = 0; hh < 16; ++hh) {
                float pre = fmaf(sW1[hh * 2], ax, fmaf(sW1[hh * 2 + 1], ay, sb1[hh]));
                pre = fmaxf(pre, 0.0f);
                a0 = fmaf(pre, sW2[e0 * 17 + hh], a0);
                a1 = fmaf(pre, sW2[(e0 + 1) * 17 + hh], a1);
            }
            const unsigned short b0 = f2bf(a0), b1v = f2bf(a1);
            #pragma unroll
            for (int bufi = 0; bufi < 2; ++bufi) {
                unsigned short* row = &sA[bufi * MT * ASTR + erow * ASTR];
                row[e0]       = b0;  row[e0 + 1]       = b1v;
                row[144 + e0] = 0;   row[144 + e0 + 1] = 0;
            }
            // initial h = z[b] (bf16) into buffer 0, cols 16..143: 16 elems/thread
            const unsigned b_idx = (unsigned)gr / 5u;
            const float4* zp = reinterpret_cast<const float4*>(z + (size_t)b_idx * 128 + esub * 16);
            const float4 z0 = zp[0], z1 = zp[1], z2 = zp[2], z3 = zp[3];
            union { u16x8 v; unsigned short us[8]; } w0, w1;
            w0.us[0]=f2bf(z0.x); w0.us[1]=f2bf(z0.y); w0.us[2]=f2bf(z0.z); w0.us[3]=f2bf(z0.w);
            w0.us[4]=f2bf(z1.x); w0.us[5]=f2bf(z1.y); w0.us[6]=f2bf(z1.z); w0.us[7]=f2bf(z1.w);
            w1.us[0]=f2bf(z2.x); w1.us[1]=f2bf(z2.y); w1.us[2]=f2bf(z2.z); w1.us[3]=f2bf(z2.w);
            w1.us[4]=f2bf(z3.x); w1.us[5]=f2bf(z3.y); w1.us[6]=f2bf(z3.z); w1.us[7]=f2bf(z3.w);
            unsigned short* hrow = &sA[erow * ASTR + 16 + esub * 16];
            *reinterpret_cast<u16x8*>(hrow)     = w0.v;
            *reinterpret_cast<u16x8*>(hrow + 8) = w1.v;
        }

        float cst[16];
        #pragma unroll
        for (int e = 0; e < 16; ++e) cst[e] = 0.0f;

        #pragma unroll
        for (int s = 0; s < HN; ++s) {
            const int cur = s & 1;
            const int nxt = cur ^ 1;
            __syncthreads();   // staging / previous-step h writes visible

            // ---- MFMA phase: all 4 m-tiles, one-mt-ahead A prefetch ----
            f32x4 acc[4][4];
            #pragma unroll
            for (int mt = 0; mt < 4; ++mt)
                #pragma unroll
                for (int t = 0; t < 4; ++t)
                    acc[mt][t] = splat4(biasv[t]);

            bf16x8 af[2][5];
            #pragma unroll
            for (int kt = 0; kt < 5; ++kt)
                af[0][kt] = *reinterpret_cast<const bf16x8*>(
                    &sA[cur * MT * ASTR + cc * ASTR + kt * 32 + quad * 8]);
            #pragma unroll
            for (int mt = 0; mt < 4; ++mt) {
                const int pb = mt & 1;
                if (mt < 3) {
                    #pragma unroll
                    for (int kt = 0; kt < 5; ++kt)
                        af[pb ^ 1][kt] = *reinterpret_cast<const bf16x8*>(
                            &sA[cur * MT * ASTR + ((mt + 1) * 16 + cc) * ASTR + kt * 32 + quad * 8]);
                }
                #pragma unroll
                for (int kt = 0; kt < 5; ++kt)
                    #pragma unroll
                    for (int t = 0; t < 4; ++t)
                        acc[mt][t] = __builtin_amdgcn_mfma_f32_16x16x32_bf16(
                            af[pb][kt], Bf[t][kt], acc[mt][t], 0, 0, 0);
            }

            // ---- pointwise phase: 16 independent elements, 7 trans each ----
            // acc_i/f/o = -log2e*pre, acc_g = 2*log2e*pre (scales folded into B)
            const int lcol = wv * 16 + cc;
            #pragma unroll
            for (int e = 0; e < 16; ++e) {
                const int mt = e >> 2, r = e & 3;
                const float Ei = __builtin_amdgcn_exp2f(acc[mt][0][r]);   // e^-i
                const float Ef = __builtin_amdgcn_exp2f(acc[mt][1][r]);   // e^-f
                const float Eg = __builtin_amdgcn_exp2f(acc[mt][2][r]);   // e^{2g}
                const float Eo = __builtin_amdgcn_exp2f(acc[mt][3][r]);   // e^-o
                const float t1  = (1.0f + Ei) * (1.0f + Eg);
                const float ef1 = 1.0f + Ef;
                const float t3  = (Eg - 1.0f) * ef1;
                const float num = fmaf(cst[e], t1, t3);
                const float cn  = num * __builtin_amdgcn_rcpf(t1 * ef1);
                cst[e] = cn;
                const float Ec = __builtin_amdgcn_exp2f(2.0f * LOG2E * cn);  // e^{2c}
                const float hn = (Ec - 1.0f) *
                    __builtin_amdgcn_rcpf((1.0f + Eo) * (1.0f + Ec));
                const int m = mt * 16 + quad * 4 + r;
                sA[nxt * MT * ASTR + m * ASTR + 16 + lcol] = f2bf_fast(hn);
            }
        }

        __syncthreads();   // final h (buffer 1) complete

        // -------- epilogue: heads; 8 threads/row, 16 l each --------
        {
            const int row = tid >> 3;    // 0..63
            const int j   = tid & 7;     // 0..7
            const unsigned short* hrow = &sA[1 * MT * ASTR + row * ASTR + 16 + j * 16];
            const u16x8 h0 = *reinterpret_cast<const u16x8*>(hrow);
            const u16x8 h1 = *reinterpret_cast<const u16x8*>(hrow + 8);
            float p = 0.f, q0 = 0.f, q1 = 0.f, q2 = 0.f;
            #pragma unroll
            for (int u = 0; u < 16; ++u) {
                const int l = j * 16 + u;
                const float hv = bf2f(u < 8 ? h0[u] : h1[u - 8]);
                p  = fmaf(hv, sWp[l], p);
                q0 = fmaf(hv, sWr[l], q0);
                q1 = fmaf(hv, sWr[128 + l], q1);
                q2 = fmaf(hv, sWr[256 + l], q2);
            }
            #pragma unroll
            for (int m = 1; m < 8; m <<= 1) {
                p  += __shfl_xor(p,  m, 64);
                q0 += __shfl_xor(q0, m, 64);
                q1 += __shfl_xor(q1, m, 64);
                q2 += __shfl_xor(q2, m, 64);
            }
            if (j == 0) {
                const int gr = r0g + row;
                const float prog  = p + bpv;
                const float rr0 = q0 + br0, rr1 = q1 + br1, rr2 = q2 + br2;
                const float rmean = (rr0 + rr1 + rr2) * (1.0f / 3.0f);
                const float s0 = sigm(rr0), s1 = sigm(rr1), s2 = sigm(rr2);
                const float sm = (s0 + s1 + s2) * (1.0f / 3.0f);
                const float d0 = s0 - sm, d1 = s1 - sm, d2 = s2 - sm;
                const float unc = (d0 * d0 + d1 * d1 + d2 * d2) * 0.5f;   // ddof=1
                out[gr]          = rmean;
                out[BK + gr]     = prog;
                out[2 * BK + gr] = unc;
                out[3 * BK + gr] = rr0;
                out[4 * BK + gr] = rr1;
                out[5 * BK + gr] = rr2;
            }
        }
        // next-tile staging writes emb/pad cols (both bufs) + buf0 h (z);
        // epilogue reads buf1 h-cols — disjoint; step-0 barrier orders the rest.
    }
}

extern "C" void kernel_launch(void* const* d_in, const int* in_sizes, int n_in,
                              void* d_out, int out_size, void* d_ws, size_t ws_size,
                              hipStream_t stream) {
    const float* z       = (const float*)d_in[0];
    const float* anchors = (const float*)d_in[1];
    const float* W1      = (const float*)d_in[2];
    const float* b1      = (const float*)d_in[3];
    const float* W2      = (const float*)d_in[4];
    const float* b2      = (const float*)d_in[5];
    const float* Wih     = (const float*)d_in[6];
    const float* Whh     = (const float*)d_in[7];
    const float* bih     = (const float*)d_in[8];
    const float* bhh     = (const float*)d_in[9];
    const float* Wp      = (const float*)d_in[10];
    const float* bp      = (const float*)d_in[11];
    const float* Wr      = (const float*)d_in[12];
    const float* br      = (const float*)d_in[13];

    hipLaunchKernelGGL(wahead_kernel, dim3(WGS), dim3(THREADS), 0, stream,
                       z, anchors, W1, b1, W2, b2, Wih, Whh, bih, bhh,
                       Wp, bp, Wr, br, (float*)d_out);
}